// Round 6
// baseline (163.567 us; speedup 1.0000x reference)
//
#include <hip/hip_runtime.h>

#define BB 4
#define CC 256
#define NN 4096

typedef __attribute__((ext_vector_type(8))) short bh8;
typedef __attribute__((ext_vector_type(4))) float f32x4;

// workspace layout (bytes)
#define WPK_OFF  0                        // 20*8*64*8 bf16 = 163840 (B-frag packed W)
#define BALL_OFF 163840                   // 320 f32
#define QBF_OFF  165888                   // B*N*32 bf16 = 1 MB
#define KBF_OFF  (165888 + 1048576)
#define VBF_OFF  (165888 + 2097152)       // B*C*N bf16 = 8 MB  -> end ~10.4 MB

typedef const __attribute__((address_space(1))) void* gas_t;
typedef __attribute__((address_space(3))) void* las_t;
__device__ inline void gld16(const void* g, void* l) {
    __builtin_amdgcn_global_load_lds((gas_t)g, (las_t)l, 16, 0, 0);
}

__device__ inline int pack2bf(float a, float b) {
    unsigned ua = __builtin_bit_cast(unsigned, a) + 0x8000u;
    unsigned ub = __builtin_bit_cast(unsigned, b) + 0x8000u;
    return (int)__builtin_amdgcn_perm(ub, ua, 0x07060302u);
}
__device__ inline short f2bf1(float a) {
    return (short)((__builtin_bit_cast(unsigned, a) + 0x8000u) >> 16);
}

// ---------------- prep: Wpk B-fragments + ball
__global__ __launch_bounds__(256) void prep_w(const float* __restrict__ Wq,
        const float* __restrict__ bq, const float* __restrict__ Wk,
        const float* __restrict__ bk, const float* __restrict__ Wv,
        const float* __restrict__ bv, short* __restrict__ Wpk,
        float* __restrict__ ball) {
    int tid = blockIdx.x * 256 + threadIdx.x;
    if (tid < 10240) {
        int lane = tid & 63;
        int fc = tid >> 6;                 // mt*8 + ck
        int mt = fc >> 3, ck = fc & 7;
        int m = mt * 16 + (lane & 15);
        int c0 = ck * 32 + (lane >> 4) * 8;
        const float* wrow;
        if (m < 32)      wrow = Wq + m * 256;
        else if (m < 64) wrow = Wk + (m - 32) * 256;
        else             wrow = Wv + (m - 64) * 256;
        int d[4];
        #pragma unroll
        for (int p = 0; p < 4; ++p)
            d[p] = pack2bf(wrow[c0 + 2 * p], wrow[c0 + 2 * p + 1]);
        *(int4*)(Wpk + tid * 8) = make_int4(d[0], d[1], d[2], d[3]);
    }
    if (tid < 320) {
        float b2 = tid < 32 ? bq[tid] : (tid < 64 ? bk[tid - 32] : bv[tid - 64]);
        ball[tid] = b2;
    }
}

// ---------------- projections as MFMA GEMM, m-split x4 (r5; measured neutral
// vs x2 -- proj is NOT a significant fraction of total; kept for the TLP)
__global__ __launch_bounds__(256) void proj(const float* __restrict__ x,
        const short* __restrict__ Wpk, const float* __restrict__ ball,
        short* __restrict__ qbf, short* __restrict__ kbf,
        short* __restrict__ vbf) {
    int t = threadIdx.x;
    int w = t >> 6, lane = t & 63, quad = lane >> 4, c15 = lane & 15;
    int tile = blockIdx.x;                 // 0..1023
    int b = tile >> 8, n0 = (tile & 255) * 16;
    const float* xb = x + (size_t)b * CC * NN;

    // A-frags: m = c15 (row n0+c15), k = quad*8+e, over 8 k-chunks of 32
    bh8 af[8];
    #pragma unroll
    for (int ck = 0; ck < 8; ++ck) {
        float v[8];
        #pragma unroll
        for (int e = 0; e < 8; ++e)
            v[e] = xb[(size_t)(ck * 32 + quad * 8 + e) * NN + n0 + c15];
        int d[4];
        #pragma unroll
        for (int p = 0; p < 4; ++p) d[p] = pack2bf(v[2 * p], v[2 * p + 1]);
        af[ck] = __builtin_bit_cast(bh8, make_int4(d[0], d[1], d[2], d[3]));
    }

    // this wave's 5 m-tiles (quarter of 20)
    #pragma unroll
    for (int mti = 0; mti < 5; ++mti) {
        int mt = w * 5 + mti;
        float bl = ball[mt * 16 + c15];
        f32x4 acc = {bl, bl, bl, bl};
        #pragma unroll
        for (int ck = 0; ck < 8; ++ck) {
            bh8 wf = *(const bh8*)(Wpk + ((mt * 8 + ck) * 64 + lane) * 8);
            acc = __builtin_amdgcn_mfma_f32_16x16x32_bf16(af[ck], wf, acc, 0, 0, 0);
        }
        if (mt < 4) {
            short* dst = (mt < 2) ? qbf : kbf;
            int m = (mt & 1) * 16 + c15;
            #pragma unroll
            for (int r = 0; r < 4; ++r)
                dst[(size_t)(b * NN + n0 + quad * 4 + r) * 32 + m] = f2bf1(acc[r]);
        } else {
            int c = mt * 16 + c15 - 64;
            int2 pk;
            pk.x = pack2bf(acc[0], acc[1]);
            pk.y = pack2bf(acc[2], acc[3]);
            *(int2*)(vbf + (size_t)b * CC * NN + (size_t)c * NN + n0 + quad * 4) = pk;
        }
    }
}

// ---------------- fused flash attention, V-from-L2 version
// r6 change: V staging through LDS DELETED. Per-step LDS traffic was
// 136 KB (V-DMA 32 + V-reads 64 (2x dup) + P-write 8 + P-read 32) ~= 1500cy
// at the LDS port -- ~70% of the measured 2150cy step. V's A-operand frag is
// a 16B contiguous per-lane load (vb + c*NN + j), the exact pattern K already
// uses from L2 (batch V = 2 MB, L2-resident per XCD: bids == b (mod 4) land
// on XCDs {b, b+4}). Waves remapped 64c x 32i -> 32c x 64i (c-block = w) so
// consumer c-ranges are disjoint: each V frag loaded from L2 exactly once
// (32 KB/step/CU -- same bytes the DMA moved, without the LDS round-trip).
// P stays in LDS (cross-wave), double-buffered, 1 __syncthreads/step; its
// WAR logic is unchanged. LDS traffic 136 -> 72 KB/step, and the L2 path
// (~40 KB/step incl. K) runs on a DIFFERENT pipe in parallel. The barrier's
// vmcnt(0) now drains only 5 same-step register loads (kfn + 4 V frags) with
// ~250cy of intra-step slack. No inline asm (r1/r2 lesson). QK/exp/P-write
// side byte-identical to the known-good r0 kernel.
__global__ __launch_bounds__(512, 2) void flash_attn(
        const short* __restrict__ qbf, const short* __restrict__ kbf,
        const short* __restrict__ vbf, const float* __restrict__ x,
        const float* __restrict__ gamma, float* __restrict__ out) {
    __shared__ char lds[17408];  // P 2x8KB @0 | lred 1KB @16384

    int bid = blockIdx.x;
    int b = bid & 3, i0 = (bid >> 2) * 64;   // batch -> XCD pair (K/V L2-resident)
    int t = threadIdx.x;
    int w = t >> 6, lane = t & 63, quad = lane >> 4, c15 = lane & 15;
    int nh = w >> 2, jsub = w & 3;

    const short* qb = qbf + (size_t)b * NN * 32;
    const short* kb = kbf + (size_t)b * NN * 32;
    const short* vb = vbf + (size_t)b * CC * NN;

    // Q fragments (B-operand), i = i0 + nh*32 (+16) + c15
    bh8 qf0 = *(const bh8*)(qb + (size_t)(i0 + nh * 32 + c15) * 32 + quad * 8);
    bh8 qf1 = *(const bh8*)(qb + (size_t)(i0 + nh * 32 + 16 + c15) * 32 + quad * 8);

    // K pointer for this wave's j-subtile (A-frags straight from L2)
    const short* kptr = kb + (size_t)(jsub * 16 + c15) * 32 + quad * 8;

    // V pointers: this wave owns c-rows w*32 .. w*32+32 (ms = 0,1)
    const short* vp0 = vb + (size_t)(w * 32 + c15) * NN + quad * 8;
    const short* vp1 = vp0 + (size_t)16 * NN;

    char* Pt = lds;
    float* lred = (float*)(lds + 16384);

    f32x4 acc[2][4];   // [ms][f]: c = w*32 + ms*16, i-block f
    #pragma unroll
    for (int ms = 0; ms < 2; ++ms)
        #pragma unroll
        for (int f = 0; f < 4; ++f) acc[ms][f] = (f32x4){0.f, 0.f, 0.f, 0.f};

    float lsum0 = 0.f, lsum1 = 0.f;
    const f32x4 initc = {-12.f, -12.f, -12.f, -12.f};  // softmax shift folded into C

    bh8 kf = *(const bh8*)kptr;    // K tile 0

    for (int jt = 0; jt < 64; ++jt) {
        int cur = jt & 1;
        // ---- early L2 loads: next K frag + this step's 4 V frags.
        // Consumed after the barrier; the syncthreads vmcnt(0) drain has the
        // whole QK+exp+pack phase (~250cy) of slack to cover L2 latency.
        bh8 kfn = *(const bh8*)(kptr + (size_t)((jt + 1) & 63) * 2048);
        size_t jo = (size_t)jt * 64;
        bh8 vf00 = *(const bh8*)(vp0 + jo);          // kk=0, ms=0
        bh8 vf01 = *(const bh8*)(vp1 + jo);          // kk=0, ms=1
        bh8 vf10 = *(const bh8*)(vp0 + jo + 32);     // kk=1, ms=0
        bh8 vf11 = *(const bh8*)(vp1 + jo + 32);     // kk=1, ms=1

        // ---- QK: S^T tile (A=K j-rows, B=Q i-cols), exp, pack, P->LDS[cur]
        f32x4 sa0 = __builtin_amdgcn_mfma_f32_16x16x32_bf16(kf, qf0, initc, 0, 0, 0);
        f32x4 sa1 = __builtin_amdgcn_mfma_f32_16x16x32_bf16(kf, qf1, initc, 0, 0, 0);
        float p0[4], p1[4];
        #pragma unroll
        for (int r = 0; r < 4; ++r) {
            p0[r] = __expf(sa0[r]); lsum0 += p0[r];
            p1[r] = __expf(sa1[r]); lsum1 += p1[r];
        }
        char* Ptc = Pt + cur * 8192;
        int g = jsub * 2 + (quad >> 1);
        int pb0 = (nh * 32 + c15) * 128 + ((g ^ (c15 & 7)) * 16) + (quad & 1) * 8;
        *(int2*)(Ptc + pb0) = make_int2(pack2bf(p0[0], p0[1]), pack2bf(p0[2], p0[3]));
        *(int2*)(Ptc + pb0 + 2048) = make_int2(pack2bf(p1[0], p1[1]), pack2bf(p1[2], p1[3]));

        // single barrier: publishes P[cur]. WAR on P[cur] vs step jt-2's
        // readers is ordered by step jt-1's barrier (double buffer).
        __syncthreads();

        // ---- PV: O^T(32c x 64i per wave) += V(A, from L2 regs) . P(B, LDS)
        #pragma unroll
        for (int kk = 0; kk < 2; ++kk) {
            int gs = ((kk * 4 + quad) ^ (c15 & 7)) * 16;
            bh8 pf[4];
            #pragma unroll
            for (int f = 0; f < 4; ++f)
                pf[f] = *(const bh8*)(Ptc + (f * 16 + c15) * 128 + gs);
            bh8 va = kk ? vf10 : vf00;
            bh8 vbb = kk ? vf11 : vf01;
            #pragma unroll
            for (int f = 0; f < 4; ++f)
                acc[0][f] = __builtin_amdgcn_mfma_f32_16x16x32_bf16(va, pf[f], acc[0][f], 0, 0, 0);
            #pragma unroll
            for (int f = 0; f < 4; ++f)
                acc[1][f] = __builtin_amdgcn_mfma_f32_16x16x32_bf16(vbb, pf[f], acc[1][f], 0, 0, 0);
        }
        kf = kfn;
    }

    // ---- softmax denominators: quad-reduce, then cross-wave (4 jsubs) via LDS
    lsum0 += __shfl_xor(lsum0, 16); lsum0 += __shfl_xor(lsum0, 32);
    lsum1 += __shfl_xor(lsum1, 16); lsum1 += __shfl_xor(lsum1, 32);
    if (lane < 16) {
        lred[w * 32 + lane] = lsum0;          // i-row (nh*32 + lane)
        lred[w * 32 + 16 + lane] = lsum1;     // i-row (nh*32 + 16 + lane)
    }
    __syncthreads();
    // l for i-block f (f = nh*2 + half): sum the 4 jsub waves sharing nh
    float linv[4];
    #pragma unroll
    for (int f = 0; f < 4; ++f) {
        int base = (f >> 1) * 4 * 32 + (f & 1) * 16 + c15;
        linv[f] = 1.0f / (lred[base] + lred[base + 32]
                        + lred[base + 64] + lred[base + 96]);
    }

    float gm = gamma[0];
    const float* xb2 = x + (size_t)b * CC * NN;
    float* ob = out + (size_t)b * CC * NN;
    #pragma unroll
    for (int ms = 0; ms < 2; ++ms) {
        #pragma unroll
        for (int f = 0; f < 4; ++f) {
            int i = i0 + f * 16 + c15;
            #pragma unroll
            for (int r = 0; r < 4; ++r) {
                int c = w * 32 + ms * 16 + quad * 4 + r;
                ob[(size_t)c * NN + i] = gm * acc[ms][f][r] * linv[f]
                                       + xb2[(size_t)c * NN + i];
            }
        }
    }
}

extern "C" void kernel_launch(void* const* d_in, const int* in_sizes, int n_in,
                              void* d_out, int out_size, void* d_ws, size_t ws_size,
                              hipStream_t stream) {
    const float* x     = (const float*)d_in[0];
    const float* Wq    = (const float*)d_in[1];
    const float* bq    = (const float*)d_in[2];
    const float* Wk    = (const float*)d_in[3];
    const float* bk    = (const float*)d_in[4];
    const float* Wv    = (const float*)d_in[5];
    const float* bv    = (const float*)d_in[6];
    const float* gamma = (const float*)d_in[7];
    float* out = (float*)d_out;
    char*  ws  = (char*)d_ws;
    short* Wpk  = (short*)(ws + WPK_OFF);
    float* ball = (float*)(ws + BALL_OFF);
    short* qbf  = (short*)(ws + QBF_OFF);
    short* kbf  = (short*)(ws + KBF_OFF);
    short* vbf  = (short*)(ws + VBF_OFF);

    prep_w<<<40, 256, 0, stream>>>(Wq, bq, Wk, bk, Wv, bv, Wpk, ball);
    proj<<<1024, 256, 0, stream>>>(x, Wpk, ball, qbf, kbf, vbf);
    flash_attn<<<256, 512, 0, stream>>>(qbf, kbf, vbf, x, gamma, out);
}

// Round 7
// 144.643 us; speedup vs baseline: 1.1308x; 1.1308x over previous
//
#include <hip/hip_runtime.h>

#define BB 4
#define CC 256
#define NN 4096

typedef __attribute__((ext_vector_type(8))) short bh8;
typedef __attribute__((ext_vector_type(4))) float f32x4;

// workspace layout (bytes)
#define WPK_OFF  0                        // 20*8*64*8 bf16 = 163840 (B-frag packed W)
#define BALL_OFF 163840                   // 320 f32
#define QBF_OFF  165888                   // B*N*32 bf16 = 1 MB
#define KBF_OFF  (165888 + 1048576)
#define VBF_OFF  (165888 + 2097152)       // B*C*N bf16 = 8 MB  -> end ~10.4 MB

typedef const __attribute__((address_space(1))) void* gas_t;
typedef __attribute__((address_space(3))) void* las_t;
__device__ inline void gld16(const void* g, void* l) {
    __builtin_amdgcn_global_load_lds((gas_t)g, (las_t)l, 16, 0, 0);
}

__device__ inline int pack2bf(float a, float b) {
    unsigned ua = __builtin_bit_cast(unsigned, a) + 0x8000u;
    unsigned ub = __builtin_bit_cast(unsigned, b) + 0x8000u;
    return (int)__builtin_amdgcn_perm(ub, ua, 0x07060302u);
}
__device__ inline short f2bf1(float a) {
    return (short)((__builtin_bit_cast(unsigned, a) + 0x8000u) >> 16);
}

// ---------------- prep: Wpk B-fragments + ball
__global__ __launch_bounds__(256) void prep_w(const float* __restrict__ Wq,
        const float* __restrict__ bq, const float* __restrict__ Wk,
        const float* __restrict__ bk, const float* __restrict__ Wv,
        const float* __restrict__ bv, short* __restrict__ Wpk,
        float* __restrict__ ball) {
    int tid = blockIdx.x * 256 + threadIdx.x;
    if (tid < 10240) {
        int lane = tid & 63;
        int fc = tid >> 6;                 // mt*8 + ck
        int mt = fc >> 3, ck = fc & 7;
        int m = mt * 16 + (lane & 15);
        int c0 = ck * 32 + (lane >> 4) * 8;
        const float* wrow;
        if (m < 32)      wrow = Wq + m * 256;
        else if (m < 64) wrow = Wk + (m - 32) * 256;
        else             wrow = Wv + (m - 64) * 256;
        int d[4];
        #pragma unroll
        for (int p = 0; p < 4; ++p)
            d[p] = pack2bf(wrow[c0 + 2 * p], wrow[c0 + 2 * p + 1]);
        *(int4*)(Wpk + tid * 8) = make_int4(d[0], d[1], d[2], d[3]);
    }
    if (tid < 320) {
        float b2 = tid < 32 ? bq[tid] : (tid < 64 ? bk[tid - 32] : bv[tid - 64]);
        ball[tid] = b2;
    }
}

// ---------------- projections as MFMA GEMM, m-split x4 (r5; measured neutral
// vs x2 -- proj is a small fraction of total; kept for the TLP)
__global__ __launch_bounds__(256) void proj(const float* __restrict__ x,
        const short* __restrict__ Wpk, const float* __restrict__ ball,
        short* __restrict__ qbf, short* __restrict__ kbf,
        short* __restrict__ vbf) {
    int t = threadIdx.x;
    int w = t >> 6, lane = t & 63, quad = lane >> 4, c15 = lane & 15;
    int tile = blockIdx.x;                 // 0..1023
    int b = tile >> 8, n0 = (tile & 255) * 16;
    const float* xb = x + (size_t)b * CC * NN;

    // A-frags: m = c15 (row n0+c15), k = quad*8+e, over 8 k-chunks of 32
    bh8 af[8];
    #pragma unroll
    for (int ck = 0; ck < 8; ++ck) {
        float v[8];
        #pragma unroll
        for (int e = 0; e < 8; ++e)
            v[e] = xb[(size_t)(ck * 32 + quad * 8 + e) * NN + n0 + c15];
        int d[4];
        #pragma unroll
        for (int p = 0; p < 4; ++p) d[p] = pack2bf(v[2 * p], v[2 * p + 1]);
        af[ck] = __builtin_bit_cast(bh8, make_int4(d[0], d[1], d[2], d[3]));
    }

    // this wave's 5 m-tiles (quarter of 20)
    #pragma unroll
    for (int mti = 0; mti < 5; ++mti) {
        int mt = w * 5 + mti;
        float bl = ball[mt * 16 + c15];
        f32x4 acc = {bl, bl, bl, bl};
        #pragma unroll
        for (int ck = 0; ck < 8; ++ck) {
            bh8 wf = *(const bh8*)(Wpk + ((mt * 8 + ck) * 64 + lane) * 8);
            acc = __builtin_amdgcn_mfma_f32_16x16x32_bf16(af[ck], wf, acc, 0, 0, 0);
        }
        if (mt < 4) {
            short* dst = (mt < 2) ? qbf : kbf;
            int m = (mt & 1) * 16 + c15;
            #pragma unroll
            for (int r = 0; r < 4; ++r)
                dst[(size_t)(b * NN + n0 + quad * 4 + r) * 32 + m] = f2bf1(acc[r]);
        } else {
            int c = mt * 16 + c15 - 64;
            int2 pk;
            pk.x = pack2bf(acc[0], acc[1]);
            pk.y = pack2bf(acc[2], acc[3]);
            *(int2*)(vbf + (size_t)b * CC * NN + (size_t)c * NN + n0 + quad * 4) = pk;
        }
    }
}

// ---------------- fused flash attention: r0 structure, 2 steps per barrier.
// The r0 step (~2200cy) = LDS-instruction floor (~1370cy: 112 ds ops + DMA
// write port) + ~800cy of barrier convergence + vmcnt(0) drain, paid 64x.
// r7: unroll to 32 periods x 2 j-tiles with ONE __syncthreads per period.
// V 4x32KB + P 4x8KB = 163840 B LDS (full 160 KiB; >64KB static proven in
// r1/r2). Per period: 2xQK + exp/pack + 2 P-writes -> barrier -> stage 2 V
// tiles (drain slack now a FULL PERIOD) -> 2xPV. WAR on P[b] (rewritten at
// period p+2) is ordered by period p+1's barrier; V staging writes bufs
// {ba^2,bb^2}, disjoint from read bufs {ba,bb}. Wrap-staging on the last
// period lands in dead buffers (tile 0 again; L2-resident, no HBM cost) and
// is drained by the epilogue __syncthreads before lred overlays V buf0.
// No inline asm (r1/r2 lesson); all waits compiler-generated.
__global__ __launch_bounds__(512, 2) void flash_attn(
        const short* __restrict__ qbf, const short* __restrict__ kbf,
        const short* __restrict__ vbf, const float* __restrict__ x,
        const float* __restrict__ gamma, float* __restrict__ out) {
    __shared__ char lds[163840];  // V 4x32KB @0 | P 4x8KB @131072 | lred overlays V buf0

    int bid = blockIdx.x;
    int b = bid & 3, i0 = (bid >> 2) * 64;   // batch -> XCD pair (K/V L2-resident)
    int t = threadIdx.x;
    int w = t >> 6, lane = t & 63, quad = lane >> 4, c15 = lane & 15;
    int mg = w & 3, nh = w >> 2, jsub = w & 3;

    const short* qb = qbf + (size_t)b * NN * 32;
    const short* kb = kbf + (size_t)b * NN * 32;
    const short* vb = vbf + (size_t)b * CC * NN;

    // Q fragments (B-operand), i = i0 + nh*32 (+16) + c15
    bh8 qf0 = *(const bh8*)(qb + (size_t)(i0 + nh * 32 + c15) * 32 + quad * 8);
    bh8 qf1 = *(const bh8*)(qb + (size_t)(i0 + nh * 32 + 16 + c15) * 32 + quad * 8);

    // V staging: lane l covers row w*32 + r*8 + (l>>3), granule (l&7)^((l>>3)&7)
    // (XOR swizzle); LDS dst is WAVE-UNIFORM (HW: lane l -> base + l*16).
    int vrow = w * 32 + (lane >> 3);
    int glog = (lane & 7) ^ ((lane >> 3) & 7);
    const short* vsg = vb + (size_t)vrow * NN + glog * 8;

    // K pointer for this wave's j-subtile (A-frags straight from global/L2)
    const short* kptr = kb + (size_t)(jsub * 16 + c15) * 32 + quad * 8;

    char* Pt = lds + 131072;
    float* lred = (float*)lds;               // overlays V buf0 (dead in epilogue)

    f32x4 acc[4][2];
    #pragma unroll
    for (int ms = 0; ms < 4; ++ms) {
        acc[ms][0] = (f32x4){0.f, 0.f, 0.f, 0.f};
        acc[ms][1] = (f32x4){0.f, 0.f, 0.f, 0.f};
    }
    float lsum0 = 0.f, lsum1 = 0.f;
    const f32x4 initc = {-12.f, -12.f, -12.f, -12.f};  // softmax shift folded into C

    // prologue: stage V tiles 0,1 into bufs 0,1; K frags for steps 0,1
    #pragma unroll
    for (int r = 0; r < 4; ++r) gld16(vsg + r * 8 * NN, lds + w * 4096 + r * 1024);
    #pragma unroll
    for (int r = 0; r < 4; ++r) gld16(vsg + 64 + r * 8 * NN, lds + 32768 + w * 4096 + r * 1024);
    bh8 kfa = *(const bh8*)kptr;
    bh8 kfb = *(const bh8*)(kptr + 2048);
    __syncthreads();   // drains vmcnt -> bufs 0,1 staged

    int g = jsub * 2 + (quad >> 1);
    int pb0 = (nh * 32 + c15) * 128 + ((g ^ (c15 & 7)) * 16) + (quad & 1) * 8;

    for (int pr = 0; pr < 32; ++pr) {
        int jt0 = pr * 2, jt1 = jt0 + 1;
        int ba = jt0 & 3, bb = jt1 & 3;    // read bufs this period
        // ---- QK both steps (A=K j-rows, B=Q i-cols), C = -12 shift
        f32x4 sa0a = __builtin_amdgcn_mfma_f32_16x16x32_bf16(kfa, qf0, initc, 0, 0, 0);
        f32x4 sa1a = __builtin_amdgcn_mfma_f32_16x16x32_bf16(kfa, qf1, initc, 0, 0, 0);
        f32x4 sa0b = __builtin_amdgcn_mfma_f32_16x16x32_bf16(kfb, qf0, initc, 0, 0, 0);
        f32x4 sa1b = __builtin_amdgcn_mfma_f32_16x16x32_bf16(kfb, qf1, initc, 0, 0, 0);
        // K prefetch for next period (independent; hides L2 latency)
        bh8 kfan = *(const bh8*)(kptr + (size_t)((jt0 + 2) & 63) * 2048);
        bh8 kfbn = *(const bh8*)(kptr + (size_t)((jt1 + 2) & 63) * 2048);
        // ---- exp, pack, P->LDS for both steps
        float pa0[4], pa1[4], pb0v[4], pb1v[4];
        #pragma unroll
        for (int r = 0; r < 4; ++r) {
            pa0[r] = __expf(sa0a[r]); lsum0 += pa0[r];
            pa1[r] = __expf(sa1a[r]); lsum1 += pa1[r];
            pb0v[r] = __expf(sa0b[r]); lsum0 += pb0v[r];
            pb1v[r] = __expf(sa1b[r]); lsum1 += pb1v[r];
        }
        char* Pa = Pt + ba * 8192;
        char* Pb = Pt + bb * 8192;
        *(int2*)(Pa + pb0) = make_int2(pack2bf(pa0[0], pa0[1]), pack2bf(pa0[2], pa0[3]));
        *(int2*)(Pa + pb0 + 2048) = make_int2(pack2bf(pa1[0], pa1[1]), pack2bf(pa1[2], pa1[3]));
        *(int2*)(Pb + pb0) = make_int2(pack2bf(pb0v[0], pb0v[1]), pack2bf(pb0v[2], pb0v[3]));
        *(int2*)(Pb + pb0 + 2048) = make_int2(pack2bf(pb1v[0], pb1v[1]), pack2bf(pb1v[2], pb1v[3]));

        // single barrier per period: publishes P[ba],P[bb]; vmcnt(0) drain
        // covers the V-DMA issued after the PREVIOUS period's barrier
        // (a full 2-step window of slack)
        __syncthreads();

        // ---- stage V tiles jt0+2, jt1+2 into bufs ba^2, bb^2 (disjoint from
        // read bufs; wraps harmlessly into dead buffers on the last period)
        {
            const short* vsA = vsg + (size_t)((jt0 + 2) & 63) * 64;
            const short* vsB = vsg + (size_t)((jt1 + 2) & 63) * 64;
            char* vdA = lds + (size_t)(ba ^ 2) * 32768 + w * 4096;
            char* vdB = lds + (size_t)(bb ^ 2) * 32768 + w * 4096;
            #pragma unroll
            for (int r = 0; r < 4; ++r) gld16(vsA + r * 8 * NN, vdA + r * 1024);
            #pragma unroll
            for (int r = 0; r < 4; ++r) gld16(vsB + r * 8 * NN, vdB + r * 1024);
        }

        // ---- PV both steps: O^T(64c x 32i per wave) += V(A) . P(B)
        #pragma unroll
        for (int st = 0; st < 2; ++st) {
            const char* Vb = lds + (size_t)(st ? bb : ba) * 32768;
            const char* Ptc = st ? Pb : Pa;
            #pragma unroll
            for (int kk = 0; kk < 2; ++kk) {
                int gs = ((kk * 4 + quad) ^ (c15 & 7)) * 16;
                bh8 pfa = *(const bh8*)(Ptc + (nh * 32 + c15) * 128 + gs);
                bh8 pfb = *(const bh8*)(Ptc + (nh * 32 + 16 + c15) * 128 + gs);
                #pragma unroll
                for (int ms = 0; ms < 4; ++ms) {
                    int c = mg * 64 + ms * 16 + c15;
                    bh8 vf = *(const bh8*)(Vb + c * 128 + gs);
                    acc[ms][0] = __builtin_amdgcn_mfma_f32_16x16x32_bf16(vf, pfa, acc[ms][0], 0, 0, 0);
                    acc[ms][1] = __builtin_amdgcn_mfma_f32_16x16x32_bf16(vf, pfb, acc[ms][1], 0, 0, 0);
                }
            }
        }
        kfa = kfan;
        kfb = kfbn;
    }

    // ---- softmax denominators: quad-reduce, then cross-wave (4 jsubs) via LDS
    lsum0 += __shfl_xor(lsum0, 16); lsum0 += __shfl_xor(lsum0, 32);
    lsum1 += __shfl_xor(lsum1, 16); lsum1 += __shfl_xor(lsum1, 32);
    __syncthreads();   // drains wrap-stage DMA + last PV reads; V buf0 now dead
    if (lane < 16) {
        lred[w * 32 + lane] = lsum0;
        lred[w * 32 + 16 + lane] = lsum1;
    }
    __syncthreads();
    float l0 = lred[(nh * 4 + 0) * 32 + c15] + lred[(nh * 4 + 1) * 32 + c15]
             + lred[(nh * 4 + 2) * 32 + c15] + lred[(nh * 4 + 3) * 32 + c15];
    float l1 = lred[(nh * 4 + 0) * 32 + 16 + c15] + lred[(nh * 4 + 1) * 32 + 16 + c15]
             + lred[(nh * 4 + 2) * 32 + 16 + c15] + lred[(nh * 4 + 3) * 32 + 16 + c15];
    float linv0 = 1.0f / l0, linv1 = 1.0f / l1;

    float gm = gamma[0];
    const float* xb2 = x + (size_t)b * CC * NN;
    float* ob = out + (size_t)b * CC * NN;
    int ia = i0 + nh * 32 + c15, ib2 = ia + 16;
    #pragma unroll
    for (int ms = 0; ms < 4; ++ms) {
        #pragma unroll
        for (int r = 0; r < 4; ++r) {
            int c = mg * 64 + ms * 16 + quad * 4 + r;
            ob[(size_t)c * NN + ia]  = gm * acc[ms][0][r] * linv0 + xb2[(size_t)c * NN + ia];
            ob[(size_t)c * NN + ib2] = gm * acc[ms][1][r] * linv1 + xb2[(size_t)c * NN + ib2];
        }
    }
}

extern "C" void kernel_launch(void* const* d_in, const int* in_sizes, int n_in,
                              void* d_out, int out_size, void* d_ws, size_t ws_size,
                              hipStream_t stream) {
    const float* x     = (const float*)d_in[0];
    const float* Wq    = (const float*)d_in[1];
    const float* bq    = (const float*)d_in[2];
    const float* Wk    = (const float*)d_in[3];
    const float* bk    = (const float*)d_in[4];
    const float* Wv    = (const float*)d_in[5];
    const float* bv    = (const float*)d_in[6];
    const float* gamma = (const float*)d_in[7];
    float* out = (float*)d_out;
    char*  ws  = (char*)d_ws;
    short* Wpk  = (short*)(ws + WPK_OFF);
    float* ball = (float*)(ws + BALL_OFF);
    short* qbf  = (short*)(ws + QBF_OFF);
    short* kbf  = (short*)(ws + KBF_OFF);
    short* vbf  = (short*)(ws + VBF_OFF);

    prep_w<<<40, 256, 0, stream>>>(Wq, bq, Wk, bk, Wv, bv, Wpk, ball);
    proj<<<1024, 256, 0, stream>>>(x, Wpk, ball, qbf, kbf, vbf);
    flash_attn<<<256, 512, 0, stream>>>(qbf, kbf, vbf, x, gamma, out);
}